// Round 1
// 199.812 us; speedup vs baseline: 1.0413x; 1.0413x over previous
//
#include <hip/hip_runtime.h>
#include <math.h>
#include <stdint.h>

// ---------------------------------------------------------------------------
// TransformerLayer (Swin-style) on MI355X. FP32 I/O; bf16 MFMA internals.
// B=2, H=W=128, C=128, NS=8 -> 64 windows x 256 tokens; HID=1024.
// R8: ffn1+ffn2 FUSED (fused_ffn) -> HID (67MB) never touches HBM.
//     Per block: 128 rows, 512 thr. A (128x256) LDS-resident; 16 chunks of
//     64 HID cols: ffn1 MFMA -> gelu -> swizzled LDS exchange -> ffn2 MFMA
//     accumulate; W1/W2 chunk prefetch overlaps ffn2. LN+residual epilogue.
// ---------------------------------------------------------------------------

typedef unsigned short u16;
typedef __attribute__((ext_vector_type(8))) short bf16x8;   // 8 bf16 (4 VGPRs)
typedef __attribute__((ext_vector_type(4))) float f32x4;
typedef __attribute__((ext_vector_type(4))) short u16x4;

__device__ __forceinline__ u16 f2b(float f) {
    unsigned int i = __float_as_uint(f);
    unsigned int r = (i + 0x7fffu + ((i >> 16) & 1u)) >> 16;
    return (u16)r;
}

// gelu via A-S 7.1.28 erf (|eps|<=5e-4): ONE transcendental (rcp).
__device__ __forceinline__ float gelu_e(float x) {
    float y = fabsf(x) * 0.70710678118f;
    float u = fmaf(y, fmaf(y, fmaf(y, fmaf(y, 0.078108f, 0.000972f),
                                   0.230389f), 0.278393f), 1.0f);
    u = u * u; u = u * u;
    float r = __builtin_amdgcn_rcpf(u);
    return fmaxf(x, 0.f) - 0.5f * fabsf(x) * r;
}

// 16B async global->LDS (m97-verified). LDS dest wave-uniform base + lane*16.
__device__ __forceinline__ void cp16(const void* g, void* l) {
    auto* gp = reinterpret_cast<const __attribute__((address_space(1))) unsigned int*>(
        reinterpret_cast<uintptr_t>(g));
    auto* lp = reinterpret_cast<__attribute__((address_space(3))) unsigned int*>(
        reinterpret_cast<uintptr_t>(l));
    __builtin_amdgcn_global_load_lds(gp, lp, 16, 0, 0);
}

// window row (b*16384 + win*256 + t) -> source-order row (b*16384 + h*128 + w)
__device__ __forceinline__ int win_map(int gm) {
    int b = gm >> 14, rr = gm & 16383;
    int win = rr >> 8, t = rr & 255;
    int wi = win >> 3, wj = win & 7, i = t >> 4, j = t & 15;
    int h = (wi * 16 + i + 8) & 127;
    int w = (wj * 16 + j + 8) & 127;
    return (b << 14) + h * 128 + w;
}

// ---------------------------------------------------------------------------
// Fused QKV: grid (256, 3). y=0: q=src@Wq, y=1: k=tgt@Wk (window layouts),
// y=2: v=tgt@Wv stored transposed per window. K=128 fully LDS-resident.
// ---------------------------------------------------------------------------
__global__ __launch_bounds__(256, 2)
void gemm_qkv(const u16* __restrict__ srcb, const u16* __restrict__ tgtb,
              const u16* __restrict__ Bt, u16* __restrict__ qw,
              u16* __restrict__ kw, u16* __restrict__ vwt)
{
    __shared__ __align__(16) u16 SMEM[32768];   // As[4][128][32] | Bs[4][128][32]
    u16* As = SMEM;
    u16* Bs = SMEM + 16384;
    u16* Ts = SMEM;                              // 128x136 epilogue overlay

    const int tid = threadIdx.x;
    const int w = tid >> 6, lane = tid & 63;
    const int lm = lane & 15, q = lane >> 4;
    const int wm = w >> 1, wn = w & 1;
    const int m0 = blockIdx.x * 128;
    const int y = blockIdx.y;
    const u16* Ab = (y == 0) ? srcb : tgtb;

#pragma unroll
    for (int s = 0; s < 4; ++s)
#pragma unroll
        for (int i = 0; i < 2; ++i) {
            int row = w * 32 + i * 16 + (lane >> 2);
            int kc = s * 32 + (lane & 3) * 8;
            cp16(Ab + (size_t)win_map(m0 + row) * 128 + kc,
                 (void*)(As + (s * 128 + w * 32 + i * 16) * 32));
            cp16(Bt + (size_t)(y * 128 + row) * 128 + kc,
                 (void*)(Bs + (s * 128 + w * 32 + i * 16) * 32));
        }
    __syncthreads();

    f32x4 acc[4][4] = {};
#pragma unroll
    for (int s = 0; s < 4; ++s) {
        bf16x8 af[4], bfr[4];
#pragma unroll
        for (int t = 0; t < 4; ++t)
            af[t] = *(const bf16x8*)(As + (s * 128 + wm * 64 + t * 16 + lm) * 32 + q * 8);
#pragma unroll
        for (int t = 0; t < 4; ++t)
            bfr[t] = *(const bf16x8*)(Bs + (s * 128 + wn * 64 + t * 16 + lm) * 32 + q * 8);
#pragma unroll
        for (int mt = 0; mt < 4; ++mt)
#pragma unroll
            for (int nt = 0; nt < 4; ++nt)
                acc[mt][nt] = __builtin_amdgcn_mfma_f32_16x16x32_bf16(
                    af[mt], bfr[nt], acc[mt][nt], 0, 0, 0);
    }

    __syncthreads();
#pragma unroll
    for (int mt = 0; mt < 4; ++mt)
#pragma unroll
        for (int nt = 0; nt < 4; ++nt)
#pragma unroll
            for (int r = 0; r < 4; ++r) {
                int rowl = wm * 64 + mt * 16 + q * 4 + r;
                int col = wn * 64 + nt * 16 + lm;
                int idx = (y == 2) ? col * 136 + rowl : rowl * 136 + col;
                Ts[idx] = f2b(acc[mt][nt][r]);
            }
    __syncthreads();
    const int c8 = (tid & 15) * 8;
#pragma unroll
    for (int i = 0; i < 8; ++i) {
        int rr = i * 16 + (tid >> 4);
        bf16x8 t = *(const bf16x8*)(Ts + rr * 136 + c8);
        if (y == 2) {
            int wix = m0 >> 8, tok0 = m0 & 255;   // vwT[(b*64+win)*128+ch][tok]
            *(bf16x8*)(vwt + (size_t)wix * 32768 + (size_t)rr * 256 + tok0 + c8) = t;
        } else {
            u16* Cv = (y == 0) ? qw : kw;
            *(bf16x8*)(Cv + (size_t)(m0 + rr) * 128 + c8) = t;
        }
    }
}

// ---------------------------------------------------------------------------
// Fused attention + msg-proj + LayerNorm, fully LDS-staged operands.
// One block = 64 Q rows of a window; grid 512. LDS: Ps 33.8KB + B32 32KB.
// ---------------------------------------------------------------------------
__global__ __launch_bounds__(256, 2)
void attn_msg(const u16* __restrict__ qw, const u16* __restrict__ kw,
              const u16* __restrict__ vt, const u16* __restrict__ wmt,
              const float* __restrict__ g, const float* __restrict__ bb,
              u16* __restrict__ msgb)
{
    __shared__ __align__(16) u16 Ps[64 * 264];   // P (stride 264); Q/Ot overlays
    __shared__ __align__(16) u16 B32[16384];     // 32KB staging buffer

    const int tid = threadIdx.x, w = tid >> 6, lane = tid & 63;
    const int lm = lane & 15, q = lane >> 4;
    const int l4r = lane >> 2, l4c = (lane & 3) * 8;
    const int bid = blockIdx.x;
    const int qc = bid & 3, win = (bid >> 2) & 63, b = bid >> 8;
    const int wi = win >> 3, wj = win & 7;
    const int q0 = qc * 64;
    const size_t wbase = (size_t)(b * 64 + win);
    const u16* kwb = kw + wbase * 256 * 128;
    const u16* qwb = qw + wbase * 256 * 128;
    const u16* vtb = vt + wbase * 128 * 256;

    // ---- stage Q (Ps overlay, [4 kt][64 row][32]) + K tok[0,128) ----
    u16* Qs = Ps;
#pragma unroll
    for (int i = 0; i < 4; ++i)
        cp16(qwb + (size_t)(q0 + w * 16 + l4r) * 128 + i * 32 + l4c,
             (void*)(Qs + (i * 64 + w * 16) * 32));
#pragma unroll
    for (int s = 0; s < 4; ++s)
#pragma unroll
        for (int i = 0; i < 2; ++i) {
            int tok = w * 32 + i * 16 + l4r;
            cp16(kwb + (size_t)tok * 128 + s * 32 + l4c,
                 (void*)(B32 + (s * 128 + w * 32 + i * 16) * 32));
        }
    __syncthreads();

    bf16x8 af[4];
#pragma unroll
    for (int kt = 0; kt < 4; ++kt)
        af[kt] = *(const bf16x8*)(Qs + (kt * 64 + w * 16 + lm) * 32 + q * 8);

    f32x4 s[16];
#pragma unroll
    for (int nt = 0; nt < 16; ++nt) { f32x4 z = {0.f, 0.f, 0.f, 0.f}; s[nt] = z; }
#pragma unroll
    for (int kt = 0; kt < 4; ++kt)
#pragma unroll
        for (int nt = 0; nt < 8; ++nt) {
            bf16x8 bf = *(const bf16x8*)(B32 + (kt * 128 + nt * 16 + lm) * 32 + q * 8);
            s[nt] = __builtin_amdgcn_mfma_f32_16x16x32_bf16(af[kt], bf, s[nt], 0, 0, 0);
        }
    __syncthreads();
    // ---- K tok[128,256) ----
#pragma unroll
    for (int ss = 0; ss < 4; ++ss)
#pragma unroll
        for (int i = 0; i < 2; ++i) {
            int tok = 128 + w * 32 + i * 16 + l4r;
            cp16(kwb + (size_t)tok * 128 + ss * 32 + l4c,
                 (void*)(B32 + (ss * 128 + w * 32 + i * 16) * 32));
        }
    __syncthreads();
#pragma unroll
    for (int kt = 0; kt < 4; ++kt)
#pragma unroll
        for (int nt = 8; nt < 16; ++nt) {
            bf16x8 bf = *(const bf16x8*)(B32 + (kt * 128 + (nt - 8) * 16 + lm) * 32 + q * 8);
            s[nt] = __builtin_amdgcn_mfma_f32_16x16x32_bf16(af[kt], bf, s[nt], 0, 0, 0);
        }
    __syncthreads();   // B32 reads done -> free for V

    // ---- issue V tok[0,128) load, then softmax (overlap) ----
#pragma unroll
    for (int tt = 0; tt < 4; ++tt)
#pragma unroll
        for (int i = 0; i < 2; ++i) {
            int ch = w * 32 + i * 16 + l4r;
            cp16(vtb + (size_t)ch * 256 + tt * 32 + l4c,
                 (void*)(B32 + (tt * 128 + w * 32 + i * 16) * 32));
        }

    // analytic Swin mask + softmax (regs), P -> Ps
    int idk[16];
#pragma unroll
    for (int nt = 0; nt < 16; ++nt) {
        int rh = (wi == 7) ? ((nt >= 8) ? 2 : 1) : 0;
        int rw = (wj == 7) ? ((lm >= 8) ? 2 : 1) : 0;
        idk[nt] = rh * 3 + rw;
    }
    const float scale = 0.08838834764831845f;
#pragma unroll
    for (int r = 0; r < 4; ++r) {
        int tq = q0 + w * 16 + q * 4 + r;
        int iq = tq >> 4, jq = tq & 15;
        int rhq = (wi == 7) ? ((iq >= 8) ? 2 : 1) : 0;
        int rwq = (wj == 7) ? ((jq >= 8) ? 2 : 1) : 0;
        int idq = rhq * 3 + rwq;
        float sv[16];
        float mx = -1e30f;
#pragma unroll
        for (int nt = 0; nt < 16; ++nt) {
            float x = s[nt][r] * scale + ((idq != idk[nt]) ? -100.f : 0.f);
            sv[nt] = x; mx = fmaxf(mx, x);
        }
        mx = fmaxf(mx, __shfl_xor(mx, 1));
        mx = fmaxf(mx, __shfl_xor(mx, 2));
        mx = fmaxf(mx, __shfl_xor(mx, 4));
        mx = fmaxf(mx, __shfl_xor(mx, 8));
        float sum = 0.f;
#pragma unroll
        for (int nt = 0; nt < 16; ++nt) { float e = __expf(sv[nt] - mx); sv[nt] = e; sum += e; }
        sum += __shfl_xor(sum, 1);
        sum += __shfl_xor(sum, 2);
        sum += __shfl_xor(sum, 4);
        sum += __shfl_xor(sum, 8);
        float inv = 1.0f / sum;
#pragma unroll
        for (int nt = 0; nt < 16; ++nt)
            Ps[(w * 16 + q * 4 + r) * 264 + nt * 16 + lm] = f2b(sv[nt] * inv);
    }
    __syncthreads();   // V0 loaded (barrier drains vmcnt) + P visible

    // ---- PV tok[0,128) ----
    f32x4 o[8];
#pragma unroll
    for (int nt = 0; nt < 8; ++nt) { f32x4 z = {0.f, 0.f, 0.f, 0.f}; o[nt] = z; }
#pragma unroll
    for (int tt = 0; tt < 4; ++tt) {
        bf16x8 pf = *(const bf16x8*)(Ps + (w * 16 + lm) * 264 + tt * 32 + q * 8);
#pragma unroll
        for (int nt = 0; nt < 8; ++nt) {
            bf16x8 vf = *(const bf16x8*)(B32 + (tt * 128 + nt * 16 + lm) * 32 + q * 8);
            o[nt] = __builtin_amdgcn_mfma_f32_16x16x32_bf16(pf, vf, o[nt], 0, 0, 0);
        }
    }
    __syncthreads();
    // ---- V tok[128,256) ----
#pragma unroll
    for (int tt = 0; tt < 4; ++tt)
#pragma unroll
        for (int i = 0; i < 2; ++i) {
            int ch = w * 32 + i * 16 + l4r;
            cp16(vtb + (size_t)ch * 256 + 128 + tt * 32 + l4c,
                 (void*)(B32 + (tt * 128 + w * 32 + i * 16) * 32));
        }
    __syncthreads();
#pragma unroll
    for (int tt = 4; tt < 8; ++tt) {
        bf16x8 pf = *(const bf16x8*)(Ps + (w * 16 + lm) * 264 + tt * 32 + q * 8);
#pragma unroll
        for (int nt = 0; nt < 8; ++nt) {
            bf16x8 vf = *(const bf16x8*)(B32 + ((tt - 4) * 128 + nt * 16 + lm) * 32 + q * 8);
            o[nt] = __builtin_amdgcn_mfma_f32_16x16x32_bf16(pf, vf, o[nt], 0, 0, 0);
        }
    }
    __syncthreads();   // V reads + P reads done

    // ---- issue Wm stage; write O -> Ot (Ps overlay, A-layout) ----
#pragma unroll
    for (int ss = 0; ss < 4; ++ss)
#pragma unroll
        for (int i = 0; i < 2; ++i) {
            int n = w * 32 + i * 16 + l4r;
            cp16(wmt + (size_t)n * 128 + ss * 32 + l4c,
                 (void*)(B32 + (ss * 128 + w * 32 + i * 16) * 32));
        }
    u16* Ot = Ps;   // [64][136]
#pragma unroll
    for (int r = 0; r < 4; ++r) {
        int rl = w * 16 + q * 4 + r;
#pragma unroll
        for (int nt = 0; nt < 8; ++nt)
            Ot[rl * 136 + nt * 16 + lm] = f2b(o[nt][r]);
    }
    __syncthreads();

    // ---- msg = O @ WmT^T (all-LDS) ----
    f32x4 macc[8];
#pragma unroll
    for (int n2 = 0; n2 < 8; ++n2) { f32x4 z = {0.f, 0.f, 0.f, 0.f}; macc[n2] = z; }
#pragma unroll
    for (int kt = 0; kt < 4; ++kt) {
        bf16x8 paf = *(const bf16x8*)(Ot + (w * 16 + lm) * 136 + kt * 32 + q * 8);
#pragma unroll
        for (int n2 = 0; n2 < 8; ++n2) {
            bf16x8 wf = *(const bf16x8*)(B32 + (kt * 128 + n2 * 16 + lm) * 32 + q * 8);
            macc[n2] = __builtin_amdgcn_mfma_f32_16x16x32_bf16(paf, wf, macc[n2], 0, 0, 0);
        }
    }

    // ---- row LN + store (source-order rows) ----
    float gv[8], bv[8];
#pragma unroll
    for (int n2 = 0; n2 < 8; ++n2) {
        int col = n2 * 16 + lm;
        gv[n2] = g[col]; bv[n2] = bb[col];
    }
#pragma unroll
    for (int r = 0; r < 4; ++r) {
        float s1 = 0.f, s2 = 0.f;
#pragma unroll
        for (int n2 = 0; n2 < 8; ++n2) {
            float v = macc[n2][r];
            s1 += v; s2 += v * v;
        }
        s1 += __shfl_xor(s1, 1); s2 += __shfl_xor(s2, 1);
        s1 += __shfl_xor(s1, 2); s2 += __shfl_xor(s2, 2);
        s1 += __shfl_xor(s1, 4); s2 += __shfl_xor(s2, 4);
        s1 += __shfl_xor(s1, 8); s2 += __shfl_xor(s2, 8);
        float mean = s1 * (1.f / 128.f);
        float var = fmaxf(s2 * (1.f / 128.f) - mean * mean, 0.f);
        float rs = rsqrtf(var + 1e-5f);
        int t = q0 + w * 16 + q * 4 + r;
        int ii = t >> 4, jj = t & 15;
        int h = (wi * 16 + ii + 8) & 127;
        int w2 = (wj * 16 + jj + 8) & 127;
        size_t orow = ((size_t)b * 16384 + h * 128 + w2) * 128;
#pragma unroll
        for (int n2 = 0; n2 < 8; ++n2)
            msgb[orow + n2 * 16 + lm] = f2b((macc[n2][r] - mean) * rs * gv[n2] + bv[n2]);
    }
}

// ---------------------------------------------------------------------------
// FUSED FFN: out = resid + LN(gelu(cat(src,msg)@W1)@W2). HID never leaves
// the CU. One block = 128 rows, 512 thr (8 waves), 144KB LDS, 256 blocks.
// Per chunk (64 HID cols x 16): ffn1 MFMA (K=256) -> gelu -> XOR-swizzled
// Gs exchange (C-layout -> A-layout transpose, bank-conflict-free) ->
// ffn2 MFMA (K=64) accumulating 128x128 fp32 in regs. W1/W2 chunk prefetch
// issued after the ffn1 barrier so loads overlap ffn2; drained at the
// loop-bottom __syncthreads. 2 barriers/chunk.
// ---------------------------------------------------------------------------
__global__ __launch_bounds__(512, 2)
void fused_ffn(const u16* __restrict__ A0, const u16* __restrict__ A1,
               const u16* __restrict__ W1T, const u16* __restrict__ W2T,
               const float* __restrict__ g, const float* __restrict__ bb,
               const float* __restrict__ resid, float* __restrict__ outv)
{
    __shared__ __align__(16) u16 As[32768];     // [8 ks][128 row][32]  64KB
    __shared__ __align__(16) u16 W1s[16384];    // [8 ks][64 row][32]   32KB
    __shared__ __align__(16) u16 W2s[16384];    // [2 st][2 ks][128][32] 32KB
    __shared__ __align__(16) u16 Gs[8192];      // [128][64] swizzled   16KB

    const int tid = threadIdx.x;
    const int w = tid >> 6, lane = tid & 63;
    const int lm = lane & 15, q = lane >> 4;
    const int l4r = lane >> 2, l4c = (lane & 3) * 8;
    const int wm = w >> 1, wn = w & 1;          // 4x2 wave grid
    const int m0 = blockIdx.x * 128;

    // ---- prologue: stage A (once, wave w = k-section w) + W1(0) + W2(0) ----
    {
        const u16* Ab = (w < 4) ? A0 : A1;      // cat(src,msg) K halves
        int kc = (w & 3) * 32 + l4c;
#pragma unroll
        for (int i = 0; i < 8; ++i)
            cp16(Ab + (size_t)(m0 + i * 16 + l4r) * 128 + kc,
                 (void*)(As + (w * 128 + i * 16) * 32));
    }
#pragma unroll
    for (int i = 0; i < 4; ++i)
        cp16(W1T + (size_t)(i * 16 + l4r) * 256 + w * 32 + l4c,
             (void*)(W1s + (w * 64 + i * 16) * 32));
    {
        int s2 = w >> 2, rg = w & 3;
#pragma unroll
        for (int i = 0; i < 2; ++i)
            cp16(W2T + (size_t)(rg * 32 + i * 16 + l4r) * 1024 + s2 * 32 + l4c,
                 (void*)(W2s + (s2 * 128 + rg * 32 + i * 16) * 32));
    }
    __syncthreads();

    f32x4 acc2[2][4] = {};                       // 128x128 block out, 32 f32/thr
    for (int c = 0; c < 16; ++c) {
        // ---- ffn1: acc1 = A @ W1chunk (128x64, K=256) ----
        f32x4 acc1[2][2] = {};
#pragma unroll
        for (int s = 0; s < 8; ++s) {
            bf16x8 af[2], bf[2];
#pragma unroll
            for (int mt = 0; mt < 2; ++mt)
                af[mt] = *(const bf16x8*)(As + (s * 128 + wm * 32 + mt * 16 + lm) * 32 + q * 8);
#pragma unroll
            for (int nt = 0; nt < 2; ++nt)
                bf[nt] = *(const bf16x8*)(W1s + (s * 64 + wn * 32 + nt * 16 + lm) * 32 + q * 8);
#pragma unroll
            for (int mt = 0; mt < 2; ++mt)
#pragma unroll
                for (int nt = 0; nt < 2; ++nt)
                    acc1[mt][nt] = __builtin_amdgcn_mfma_f32_16x16x32_bf16(
                        af[mt], bf[nt], acc1[mt][nt], 0, 0, 0);
        }

        // ---- gelu -> Gs (XOR-swizzled: slot ^= row&7; kills the 128B-stride
        //      16-way bank conflict on the ffn2 A-fragment reads) ----
#pragma unroll
        for (int mt = 0; mt < 2; ++mt)
#pragma unroll
            for (int nt = 0; nt < 2; ++nt)
#pragma unroll
                for (int r = 0; r < 4; ++r) {
                    int row = wm * 32 + mt * 16 + q * 4 + r;
                    int col = wn * 32 + nt * 16 + lm;
                    int idx = row * 64 + ((((col >> 3) ^ (row & 7))) << 3) + (col & 7);
                    Gs[idx] = f2b(gelu_e(acc1[mt][nt][r]));
                }
        __syncthreads();   // A: all ffn1 W1s reads done; Gs visible

        // ---- prefetch W1(c+1), W2(c+1) -> overlaps ffn2 below ----
        if (c + 1 < 16) {
#pragma unroll
            for (int i = 0; i < 4; ++i)
                cp16(W1T + (size_t)((c + 1) * 64 + i * 16 + l4r) * 256 + w * 32 + l4c,
                     (void*)(W1s + (w * 64 + i * 16) * 32));
            int s2 = w >> 2, rg = w & 3;
            int st = (c + 1) & 1;
#pragma unroll
            for (int i = 0; i < 2; ++i)
                cp16(W2T + (size_t)(rg * 32 + i * 16 + l4r) * 1024
                         + (c + 1) * 64 + s2 * 32 + l4c,
                     (void*)(W2s + st * 8192 + (s2 * 128 + rg * 32 + i * 16) * 32));
        }

        // ---- ffn2: acc2 += gelu_tile @ W2chunk (128x128, K=64) ----
        const u16* W2p = W2s + (c & 1) * 8192;
#pragma unroll
        for (int ks = 0; ks < 2; ++ks) {
            bf16x8 pa[2], wf[4];
#pragma unroll
            for (int mt = 0; mt < 2; ++mt) {
                int row = wm * 32 + mt * 16 + lm;
                pa[mt] = *(const bf16x8*)(Gs + row * 64
                                          + ((((ks << 2) + q) ^ (row & 7)) << 3));
            }
#pragma unroll
            for (int nt = 0; nt < 4; ++nt)
                wf[nt] = *(const bf16x8*)(W2p + (ks * 128 + wn * 64 + nt * 16 + lm) * 32 + q * 8);
#pragma unroll
            for (int mt = 0; mt < 2; ++mt)
#pragma unroll
                for (int nt = 0; nt < 4; ++nt)
                    acc2[mt][nt] = __builtin_amdgcn_mfma_f32_16x16x32_bf16(
                        pa[mt], wf[nt], acc2[mt][nt], 0, 0, 0);
        }
        __syncthreads();   // B: drains vmcnt (W(c+1) ready); Gs reads done
    }

    // ---- LN + residual epilogue (stats exchange overlaid on Gs) ----
    float* stats = (float*)Gs;                   // [128][4] = 2KB
#pragma unroll
    for (int mt = 0; mt < 2; ++mt)
#pragma unroll
        for (int r = 0; r < 4; ++r) {
            float s1 = 0.f, s2 = 0.f;
#pragma unroll
            for (int nt = 0; nt < 4; ++nt) {
                float v = acc2[mt][nt][r];
                s1 += v; s2 += v * v;
            }
            s1 += __shfl_xor(s1, 1); s2 += __shfl_xor(s2, 1);
            s1 += __shfl_xor(s1, 2); s2 += __shfl_xor(s2, 2);
            s1 += __shfl_xor(s1, 4); s2 += __shfl_xor(s2, 4);
            s1 += __shfl_xor(s1, 8); s2 += __shfl_xor(s2, 8);
            if (lm == 0) {
                int row = wm * 32 + mt * 16 + q * 4 + r;
                stats[row * 4 + wn * 2] = s1;
                stats[row * 4 + wn * 2 + 1] = s2;
            }
        }
    __syncthreads();

    float gv[4], bv[4];
#pragma unroll
    for (int nt = 0; nt < 4; ++nt) {
        int col = wn * 64 + nt * 16 + lm;
        gv[nt] = g[col]; bv[nt] = bb[col];
    }
#pragma unroll
    for (int mt = 0; mt < 2; ++mt)
#pragma unroll
        for (int r = 0; r < 4; ++r) {
            int row = wm * 32 + mt * 16 + q * 4 + r;
            f32x4 st = *(const f32x4*)(stats + row * 4);
            float mean = (st[0] + st[2]) * (1.f / 128.f);
            float var = fmaxf((st[1] + st[3]) * (1.f / 128.f) - mean * mean, 0.f);
            float rs = rsqrtf(var + 1e-5f);
#pragma unroll
            for (int nt = 0; nt < 4; ++nt) {
                int col = wn * 64 + nt * 16 + lm;
                size_t gi = (size_t)(m0 + row) * 128 + col;
                outv[gi] = (acc2[mt][nt][r] - mean) * rs * gv[nt] + bv[nt] + resid[gi];
            }
        }
}

// ---------------------------------------------------------------------------
// Prep (merged): weight transposes write-coalesced; fp32->bf16 act cast.
// ---------------------------------------------------------------------------
__global__ void prep_all(const float* __restrict__ Wq, const float* __restrict__ Wk,
                         const float* __restrict__ Wv, const float* __restrict__ Wm,
                         const float* __restrict__ W1, const float* __restrict__ W2,
                         const float* __restrict__ src, const float* __restrict__ tgt,
                         u16* __restrict__ ws, u16* __restrict__ srcb,
                         u16* __restrict__ tgtb)
{
    int bx = blockIdx.x;
    if (bx < 1792) {
        int idx = bx * 256 + threadIdx.x;
        if (idx < 65536) {                       // Wq,Wk,Wv,Wm: 128x128
            int m = idx >> 14, e = idx & 16383;
            const float* sp = (m == 0) ? Wq : (m == 1) ? Wk : (m == 2) ? Wv : Wm;
            int n = e >> 7, k = e & 127;
            ws[m * 16384 + n * 128 + k] = f2b(sp[k * 128 + n]);
        } else if (idx < 327680) {               // W1 (256,1024) -> (1024,256)
            int e = idx - 65536;
            int n = e >> 8, k = e & 255;
            ws[65536 + n * 256 + k] = f2b(W1[k * 1024 + n]);
        } else {                                  // W2 (1024,128) -> (128,1024)
            int e = idx - 327680;
            int n = e >> 10, k = e & 1023;
            ws[327680 + n * 1024 + k] = f2b(W2[k * 128 + n]);
        }
    } else {
        int idx = (bx - 1792) * 256 + threadIdx.x;   // 0..2097151
        const float* s; u16* d; int i;
        if (idx < 1048576) { s = src; d = srcb; i = idx * 4; }
        else               { s = tgt; d = tgtb; i = (idx - 1048576) * 4; }
        f32x4 v = *(const f32x4*)(s + i);
        u16x4 o; o[0] = f2b(v[0]); o[1] = f2b(v[1]); o[2] = f2b(v[2]); o[3] = f2b(v[3]);
        *(u16x4*)(d + i) = o;
    }
}

// ---------------------------------------------------------------------------
// Workspace layout (u16 element offsets)
// ---------------------------------------------------------------------------
#define OFF_WQT  0u            // concat [WqT;WkT;WvT] 3x(128x128)
#define OFF_WMT  49152u
#define OFF_W1T  65536u
#define OFF_W2T  327680u
#define OFF_SRCB 458752u
#define OFF_TGTB 4653056u
#define OFF_QW   8847360u
#define OFF_KW   13041664u
#define OFF_VWT  17235968u
#define OFF_MSGB 21430272u     // bf16 msg, source-order; ends 25624576

extern "C" void kernel_launch(void* const* d_in, const int* in_sizes, int n_in,
                              void* d_out, int out_size, void* d_ws, size_t ws_size,
                              hipStream_t stream)
{
    (void)in_sizes; (void)n_in; (void)out_size; (void)ws_size;
    const float* source = (const float*)d_in[0];
    const float* target = (const float*)d_in[1];
    const float* Wq = (const float*)d_in[2];
    const float* Wk = (const float*)d_in[3];
    const float* Wv = (const float*)d_in[4];
    const float* Wm = (const float*)d_in[5];
    const float* g1 = (const float*)d_in[6];
    const float* b1 = (const float*)d_in[7];
    const float* W1 = (const float*)d_in[8];
    const float* W2 = (const float*)d_in[9];
    const float* g2 = (const float*)d_in[10];
    const float* b2 = (const float*)d_in[11];
    u16* ws = (u16*)d_ws;
    float* out = (float*)d_out;

    prep_all<<<9984, 256, 0, stream>>>(Wq, Wk, Wv, Wm, W1, W2, source, target,
                                       ws, ws + OFF_SRCB, ws + OFF_TGTB);
    gemm_qkv<<<dim3(256, 3), 256, 0, stream>>>(
        ws + OFF_SRCB, ws + OFF_TGTB, ws + OFF_WQT,
        ws + OFF_QW, ws + OFF_KW, ws + OFF_VWT);
    attn_msg<<<512, 256, 0, stream>>>(
        ws + OFF_QW, ws + OFF_KW, ws + OFF_VWT, ws + OFF_WMT, g1, b1,
        ws + OFF_MSGB);
    fused_ffn<<<256, 512, 0, stream>>>(
        ws + OFF_SRCB, ws + OFF_MSGB, ws + OFF_W1T, ws + OFF_W2T,
        g2, b2, source, out);
}

// Round 2
// 192.193 us; speedup vs baseline: 1.0825x; 1.0396x over previous
//
#include <hip/hip_runtime.h>
#include <math.h>
#include <stdint.h>

// ---------------------------------------------------------------------------
// TransformerLayer (Swin-style) on MI355X. FP32 I/O; bf16 MFMA internals.
// B=2, H=W=128, C=128, NS=8 -> 64 windows x 256 tokens; HID=1024.
// R9: fused_ffn rebuilt for LDS-BW + occupancy. A (cat(src,msg)) lives in
//     registers (64 VGPR); ffn1 uses swapped MFMA operands so gelu output
//     packs to 8B swizzled LDS writes via v_cvt_pk_bf16_f32; W1/W2 double-
//     buffered (112KB LDS); 1024 thr -> 4 waves/SIMD.
// ---------------------------------------------------------------------------

typedef unsigned short u16;
typedef __attribute__((ext_vector_type(8))) short bf16x8;   // 8 bf16 (4 VGPRs)
typedef __attribute__((ext_vector_type(4))) float f32x4;
typedef __attribute__((ext_vector_type(4))) short u16x4;
typedef __attribute__((ext_vector_type(2))) unsigned int u32x2;

__device__ __forceinline__ u16 f2b(float f) {
    unsigned int i = __float_as_uint(f);
    unsigned int r = (i + 0x7fffu + ((i >> 16) & 1u)) >> 16;
    return (u16)r;
}

// gelu via A-S 7.1.28 erf (|eps|<=5e-4): ONE transcendental (rcp).
__device__ __forceinline__ float gelu_e(float x) {
    float y = fabsf(x) * 0.70710678118f;
    float u = fmaf(y, fmaf(y, fmaf(y, fmaf(y, 0.078108f, 0.000972f),
                                   0.230389f), 0.278393f), 1.0f);
    u = u * u; u = u * u;
    float r = __builtin_amdgcn_rcpf(u);
    return fmaxf(x, 0.f) - 0.5f * fabsf(x) * r;
}

// 16B async global->LDS (m97-verified). LDS dest wave-uniform base + lane*16.
__device__ __forceinline__ void cp16(const void* g, void* l) {
    auto* gp = reinterpret_cast<const __attribute__((address_space(1))) unsigned int*>(
        reinterpret_cast<uintptr_t>(g));
    auto* lp = reinterpret_cast<__attribute__((address_space(3))) unsigned int*>(
        reinterpret_cast<uintptr_t>(l));
    __builtin_amdgcn_global_load_lds(gp, lp, 16, 0, 0);
}

// window row (b*16384 + win*256 + t) -> source-order row (b*16384 + h*128 + w)
__device__ __forceinline__ int win_map(int gm) {
    int b = gm >> 14, rr = gm & 16383;
    int win = rr >> 8, t = rr & 255;
    int wi = win >> 3, wj = win & 7, i = t >> 4, j = t & 15;
    int h = (wi * 16 + i + 8) & 127;
    int w = (wj * 16 + j + 8) & 127;
    return (b << 14) + h * 128 + w;
}

// ---------------------------------------------------------------------------
// Fused QKV: grid (256, 3). y=0: q=src@Wq, y=1: k=tgt@Wk (window layouts),
// y=2: v=tgt@Wv stored transposed per window. K=128 fully LDS-resident.
// ---------------------------------------------------------------------------
__global__ __launch_bounds__(256, 2)
void gemm_qkv(const u16* __restrict__ srcb, const u16* __restrict__ tgtb,
              const u16* __restrict__ Bt, u16* __restrict__ qw,
              u16* __restrict__ kw, u16* __restrict__ vwt)
{
    __shared__ __align__(16) u16 SMEM[32768];   // As[4][128][32] | Bs[4][128][32]
    u16* As = SMEM;
    u16* Bs = SMEM + 16384;
    u16* Ts = SMEM;                              // 128x136 epilogue overlay

    const int tid = threadIdx.x;
    const int w = tid >> 6, lane = tid & 63;
    const int lm = lane & 15, q = lane >> 4;
    const int wm = w >> 1, wn = w & 1;
    const int m0 = blockIdx.x * 128;
    const int y = blockIdx.y;
    const u16* Ab = (y == 0) ? srcb : tgtb;

#pragma unroll
    for (int s = 0; s < 4; ++s)
#pragma unroll
        for (int i = 0; i < 2; ++i) {
            int row = w * 32 + i * 16 + (lane >> 2);
            int kc = s * 32 + (lane & 3) * 8;
            cp16(Ab + (size_t)win_map(m0 + row) * 128 + kc,
                 (void*)(As + (s * 128 + w * 32 + i * 16) * 32));
            cp16(Bt + (size_t)(y * 128 + row) * 128 + kc,
                 (void*)(Bs + (s * 128 + w * 32 + i * 16) * 32));
        }
    __syncthreads();

    f32x4 acc[4][4] = {};
#pragma unroll
    for (int s = 0; s < 4; ++s) {
        bf16x8 af[4], bfr[4];
#pragma unroll
        for (int t = 0; t < 4; ++t)
            af[t] = *(const bf16x8*)(As + (s * 128 + wm * 64 + t * 16 + lm) * 32 + q * 8);
#pragma unroll
        for (int t = 0; t < 4; ++t)
            bfr[t] = *(const bf16x8*)(Bs + (s * 128 + wn * 64 + t * 16 + lm) * 32 + q * 8);
#pragma unroll
        for (int mt = 0; mt < 4; ++mt)
#pragma unroll
            for (int nt = 0; nt < 4; ++nt)
                acc[mt][nt] = __builtin_amdgcn_mfma_f32_16x16x32_bf16(
                    af[mt], bfr[nt], acc[mt][nt], 0, 0, 0);
    }

    __syncthreads();
#pragma unroll
    for (int mt = 0; mt < 4; ++mt)
#pragma unroll
        for (int nt = 0; nt < 4; ++nt)
#pragma unroll
            for (int r = 0; r < 4; ++r) {
                int rowl = wm * 64 + mt * 16 + q * 4 + r;
                int col = wn * 64 + nt * 16 + lm;
                int idx = (y == 2) ? col * 136 + rowl : rowl * 136 + col;
                Ts[idx] = f2b(acc[mt][nt][r]);
            }
    __syncthreads();
    const int c8 = (tid & 15) * 8;
#pragma unroll
    for (int i = 0; i < 8; ++i) {
        int rr = i * 16 + (tid >> 4);
        bf16x8 t = *(const bf16x8*)(Ts + rr * 136 + c8);
        if (y == 2) {
            int wix = m0 >> 8, tok0 = m0 & 255;   // vwT[(b*64+win)*128+ch][tok]
            *(bf16x8*)(vwt + (size_t)wix * 32768 + (size_t)rr * 256 + tok0 + c8) = t;
        } else {
            u16* Cv = (y == 0) ? qw : kw;
            *(bf16x8*)(Cv + (size_t)(m0 + rr) * 128 + c8) = t;
        }
    }
}

// ---------------------------------------------------------------------------
// Fused attention + msg-proj + LayerNorm, fully LDS-staged operands.
// One block = 64 Q rows of a window; grid 512. LDS: Ps 33.8KB + B32 32KB.
// ---------------------------------------------------------------------------
__global__ __launch_bounds__(256, 2)
void attn_msg(const u16* __restrict__ qw, const u16* __restrict__ kw,
              const u16* __restrict__ vt, const u16* __restrict__ wmt,
              const float* __restrict__ g, const float* __restrict__ bb,
              u16* __restrict__ msgb)
{
    __shared__ __align__(16) u16 Ps[64 * 264];   // P (stride 264); Q/Ot overlays
    __shared__ __align__(16) u16 B32[16384];     // 32KB staging buffer

    const int tid = threadIdx.x, w = tid >> 6, lane = tid & 63;
    const int lm = lane & 15, q = lane >> 4;
    const int l4r = lane >> 2, l4c = (lane & 3) * 8;
    const int bid = blockIdx.x;
    const int qc = bid & 3, win = (bid >> 2) & 63, b = bid >> 8;
    const int wi = win >> 3, wj = win & 7;
    const int q0 = qc * 64;
    const size_t wbase = (size_t)(b * 64 + win);
    const u16* kwb = kw + wbase * 256 * 128;
    const u16* qwb = qw + wbase * 256 * 128;
    const u16* vtb = vt + wbase * 128 * 256;

    // ---- stage Q (Ps overlay, [4 kt][64 row][32]) + K tok[0,128) ----
    u16* Qs = Ps;
#pragma unroll
    for (int i = 0; i < 4; ++i)
        cp16(qwb + (size_t)(q0 + w * 16 + l4r) * 128 + i * 32 + l4c,
             (void*)(Qs + (i * 64 + w * 16) * 32));
#pragma unroll
    for (int s = 0; s < 4; ++s)
#pragma unroll
        for (int i = 0; i < 2; ++i) {
            int tok = w * 32 + i * 16 + l4r;
            cp16(kwb + (size_t)tok * 128 + s * 32 + l4c,
                 (void*)(B32 + (s * 128 + w * 32 + i * 16) * 32));
        }
    __syncthreads();

    bf16x8 af[4];
#pragma unroll
    for (int kt = 0; kt < 4; ++kt)
        af[kt] = *(const bf16x8*)(Qs + (kt * 64 + w * 16 + lm) * 32 + q * 8);

    f32x4 s[16];
#pragma unroll
    for (int nt = 0; nt < 16; ++nt) { f32x4 z = {0.f, 0.f, 0.f, 0.f}; s[nt] = z; }
#pragma unroll
    for (int kt = 0; kt < 4; ++kt)
#pragma unroll
        for (int nt = 0; nt < 8; ++nt) {
            bf16x8 bf = *(const bf16x8*)(B32 + (kt * 128 + nt * 16 + lm) * 32 + q * 8);
            s[nt] = __builtin_amdgcn_mfma_f32_16x16x32_bf16(af[kt], bf, s[nt], 0, 0, 0);
        }
    __syncthreads();
    // ---- K tok[128,256) ----
#pragma unroll
    for (int ss = 0; ss < 4; ++ss)
#pragma unroll
        for (int i = 0; i < 2; ++i) {
            int tok = 128 + w * 32 + i * 16 + l4r;
            cp16(kwb + (size_t)tok * 128 + ss * 32 + l4c,
                 (void*)(B32 + (ss * 128 + w * 32 + i * 16) * 32));
        }
    __syncthreads();
#pragma unroll
    for (int kt = 0; kt < 4; ++kt)
#pragma unroll
        for (int nt = 8; nt < 16; ++nt) {
            bf16x8 bf = *(const bf16x8*)(B32 + (kt * 128 + (nt - 8) * 16 + lm) * 32 + q * 8);
            s[nt] = __builtin_amdgcn_mfma_f32_16x16x32_bf16(af[kt], bf, s[nt], 0, 0, 0);
        }
    __syncthreads();   // B32 reads done -> free for V

    // ---- issue V tok[0,128) load, then softmax (overlap) ----
#pragma unroll
    for (int tt = 0; tt < 4; ++tt)
#pragma unroll
        for (int i = 0; i < 2; ++i) {
            int ch = w * 32 + i * 16 + l4r;
            cp16(vtb + (size_t)ch * 256 + tt * 32 + l4c,
                 (void*)(B32 + (tt * 128 + w * 32 + i * 16) * 32));
        }

    // analytic Swin mask + softmax (regs), P -> Ps
    int idk[16];
#pragma unroll
    for (int nt = 0; nt < 16; ++nt) {
        int rh = (wi == 7) ? ((nt >= 8) ? 2 : 1) : 0;
        int rw = (wj == 7) ? ((lm >= 8) ? 2 : 1) : 0;
        idk[nt] = rh * 3 + rw;
    }
    const float scale = 0.08838834764831845f;
#pragma unroll
    for (int r = 0; r < 4; ++r) {
        int tq = q0 + w * 16 + q * 4 + r;
        int iq = tq >> 4, jq = tq & 15;
        int rhq = (wi == 7) ? ((iq >= 8) ? 2 : 1) : 0;
        int rwq = (wj == 7) ? ((jq >= 8) ? 2 : 1) : 0;
        int idq = rhq * 3 + rwq;
        float sv[16];
        float mx = -1e30f;
#pragma unroll
        for (int nt = 0; nt < 16; ++nt) {
            float x = s[nt][r] * scale + ((idq != idk[nt]) ? -100.f : 0.f);
            sv[nt] = x; mx = fmaxf(mx, x);
        }
        mx = fmaxf(mx, __shfl_xor(mx, 1));
        mx = fmaxf(mx, __shfl_xor(mx, 2));
        mx = fmaxf(mx, __shfl_xor(mx, 4));
        mx = fmaxf(mx, __shfl_xor(mx, 8));
        float sum = 0.f;
#pragma unroll
        for (int nt = 0; nt < 16; ++nt) { float e = __expf(sv[nt] - mx); sv[nt] = e; sum += e; }
        sum += __shfl_xor(sum, 1);
        sum += __shfl_xor(sum, 2);
        sum += __shfl_xor(sum, 4);
        sum += __shfl_xor(sum, 8);
        float inv = 1.0f / sum;
#pragma unroll
        for (int nt = 0; nt < 16; ++nt)
            Ps[(w * 16 + q * 4 + r) * 264 + nt * 16 + lm] = f2b(sv[nt] * inv);
    }
    __syncthreads();   // V0 loaded (barrier drains vmcnt) + P visible

    // ---- PV tok[0,128) ----
    f32x4 o[8];
#pragma unroll
    for (int nt = 0; nt < 8; ++nt) { f32x4 z = {0.f, 0.f, 0.f, 0.f}; o[nt] = z; }
#pragma unroll
    for (int tt = 0; tt < 4; ++tt) {
        bf16x8 pf = *(const bf16x8*)(Ps + (w * 16 + lm) * 264 + tt * 32 + q * 8);
#pragma unroll
        for (int nt = 0; nt < 8; ++nt) {
            bf16x8 vf = *(const bf16x8*)(B32 + (tt * 128 + nt * 16 + lm) * 32 + q * 8);
            o[nt] = __builtin_amdgcn_mfma_f32_16x16x32_bf16(pf, vf, o[nt], 0, 0, 0);
        }
    }
    __syncthreads();
    // ---- V tok[128,256) ----
#pragma unroll
    for (int tt = 0; tt < 4; ++tt)
#pragma unroll
        for (int i = 0; i < 2; ++i) {
            int ch = w * 32 + i * 16 + l4r;
            cp16(vtb + (size_t)ch * 256 + 128 + tt * 32 + l4c,
                 (void*)(B32 + (tt * 128 + w * 32 + i * 16) * 32));
        }
    __syncthreads();
#pragma unroll
    for (int tt = 4; tt < 8; ++tt) {
        bf16x8 pf = *(const bf16x8*)(Ps + (w * 16 + lm) * 264 + tt * 32 + q * 8);
#pragma unroll
        for (int nt = 0; nt < 8; ++nt) {
            bf16x8 vf = *(const bf16x8*)(B32 + ((tt - 4) * 128 + nt * 16 + lm) * 32 + q * 8);
            o[nt] = __builtin_amdgcn_mfma_f32_16x16x32_bf16(pf, vf, o[nt], 0, 0, 0);
        }
    }
    __syncthreads();   // V reads + P reads done

    // ---- issue Wm stage; write O -> Ot (Ps overlay, A-layout) ----
#pragma unroll
    for (int ss = 0; ss < 4; ++ss)
#pragma unroll
        for (int i = 0; i < 2; ++i) {
            int n = w * 32 + i * 16 + l4r;
            cp16(wmt + (size_t)n * 128 + ss * 32 + l4c,
                 (void*)(B32 + (ss * 128 + w * 32 + i * 16) * 32));
        }
    u16* Ot = Ps;   // [64][136]
#pragma unroll
    for (int r = 0; r < 4; ++r) {
        int rl = w * 16 + q * 4 + r;
#pragma unroll
        for (int nt = 0; nt < 8; ++nt)
            Ot[rl * 136 + nt * 16 + lm] = f2b(o[nt][r]);
    }
    __syncthreads();

    // ---- msg = O @ WmT^T (all-LDS) ----
    f32x4 macc[8];
#pragma unroll
    for (int n2 = 0; n2 < 8; ++n2) { f32x4 z = {0.f, 0.f, 0.f, 0.f}; macc[n2] = z; }
#pragma unroll
    for (int kt = 0; kt < 4; ++kt) {
        bf16x8 paf = *(const bf16x8*)(Ot + (w * 16 + lm) * 136 + kt * 32 + q * 8);
#pragma unroll
        for (int n2 = 0; n2 < 8; ++n2) {
            bf16x8 wf = *(const bf16x8*)(B32 + (kt * 128 + n2 * 16 + lm) * 32 + q * 8);
            macc[n2] = __builtin_amdgcn_mfma_f32_16x16x32_bf16(paf, wf, macc[n2], 0, 0, 0);
        }
    }

    // ---- row LN + store (source-order rows) ----
    float gv[8], bv[8];
#pragma unroll
    for (int n2 = 0; n2 < 8; ++n2) {
        int col = n2 * 16 + lm;
        gv[n2] = g[col]; bv[n2] = bb[col];
    }
#pragma unroll
    for (int r = 0; r < 4; ++r) {
        float s1 = 0.f, s2 = 0.f;
#pragma unroll
        for (int n2 = 0; n2 < 8; ++n2) {
            float v = macc[n2][r];
            s1 += v; s2 += v * v;
        }
        s1 += __shfl_xor(s1, 1); s2 += __shfl_xor(s2, 1);
        s1 += __shfl_xor(s1, 2); s2 += __shfl_xor(s2, 2);
        s1 += __shfl_xor(s1, 4); s2 += __shfl_xor(s2, 4);
        s1 += __shfl_xor(s1, 8); s2 += __shfl_xor(s2, 8);
        float mean = s1 * (1.f / 128.f);
        float var = fmaxf(s2 * (1.f / 128.f) - mean * mean, 0.f);
        float rs = rsqrtf(var + 1e-5f);
        int t = q0 + w * 16 + q * 4 + r;
        int ii = t >> 4, jj = t & 15;
        int h = (wi * 16 + ii + 8) & 127;
        int w2 = (wj * 16 + jj + 8) & 127;
        size_t orow = ((size_t)b * 16384 + h * 128 + w2) * 128;
#pragma unroll
        for (int n2 = 0; n2 < 8; ++n2)
            msgb[orow + n2 * 16 + lm] = f2b((macc[n2][r] - mean) * rs * gv[n2] + bv[n2]);
    }
}

// ---------------------------------------------------------------------------
// FUSED FFN R9: out = resid + LN(gelu(cat(src,msg)@W1)@W2).
// 1024 thr (16 waves, 4/SIMD), 112KB LDS, grid 256 (128 rows/block).
// A (128x256 bf16) lives in REGISTERS (replicated per token-block wave
// group). Per 64-col chunk: ffn1 MFMA with SWAPPED operands (D row = HID,
// col = token) so each lane holds 4 consecutive HID values for one token ->
// cvt_pk_bf16 + one 8B swizzled Gs write. ffn2 reads 16B swizzled slots.
// W1/W2 double-buffered; prefetch issued at chunk top (full-chunk window).
// ---------------------------------------------------------------------------
__global__ __launch_bounds__(1024, 4)
void fused_ffn(const u16* __restrict__ A0, const u16* __restrict__ A1,
               const u16* __restrict__ W1T, const u16* __restrict__ W2T,
               const float* __restrict__ g, const float* __restrict__ bb,
               const float* __restrict__ resid, float* __restrict__ outv)
{
    __shared__ __align__(16) u16 W1s[32768];    // [2 buf][8 ks][64 hid][32] 64KB
    __shared__ __align__(16) u16 W2s[16384];    // [2 buf][2 ks][128 col][32] 32KB
    __shared__ __align__(16) u16 Gs[8192];      // [128 tok][64 k] swizzled 16KB

    const int tid = threadIdx.x;
    const int w = tid >> 6, lane = tid & 63;
    const int lm = lane & 15, q = lane >> 4;
    const int l4r = lane >> 2, l4c = (lane & 3) * 8;
    const int wm = w >> 2, wn = w & 3;          // token-block 32 / (hid16|col32)-block
    const int m0 = blockIdx.x * 128;

    const int s_ks = w >> 1, s_hh = (w & 1) * 32;   // W1 stage mapping
    const int s_s2 = w >> 3, s_rg = w & 7;          // W2 stage mapping

    // ---- prologue: A -> regs (one-time), W1(0)/W2(0) -> buf0 ----
    bf16x8 areg[2][8];
#pragma unroll
    for (int mt = 0; mt < 2; ++mt)
#pragma unroll
        for (int ks = 0; ks < 8; ++ks) {
            const u16* Ab = (ks < 4) ? A0 : A1;
            areg[mt][ks] = *(const bf16x8*)(
                Ab + (size_t)(m0 + wm * 32 + mt * 16 + lm) * 128 + (ks & 3) * 32 + q * 8);
        }
#pragma unroll
    for (int i = 0; i < 2; ++i)
        cp16(W1T + (size_t)(s_hh + i * 16 + l4r) * 256 + s_ks * 32 + l4c,
             (void*)(W1s + (s_ks * 64 + s_hh + i * 16) * 32));
    cp16(W2T + (size_t)(s_rg * 16 + l4r) * 1024 + s_s2 * 32 + l4c,
         (void*)(W2s + (s_s2 * 128 + s_rg * 16) * 32));
    __syncthreads();

    f32x4 acc2[2][2] = {};                       // 32x32 out tile per wave
    for (int c = 0; c < 16; ++c) {
        const int cur = c & 1;
        const u16* W1c = W1s + cur * 16384;
        const u16* W2c = W2s + cur * 8192;
        // ---- prefetch next weights into other buffer (full-chunk window) ----
        if (c < 15) {
            u16* W1n = W1s + (cur ^ 1) * 16384;
            u16* W2n = W2s + (cur ^ 1) * 8192;
#pragma unroll
            for (int i = 0; i < 2; ++i)
                cp16(W1T + (size_t)((c + 1) * 64 + s_hh + i * 16 + l4r) * 256 + s_ks * 32 + l4c,
                     (void*)(W1n + (s_ks * 64 + s_hh + i * 16) * 32));
            cp16(W2T + (size_t)(s_rg * 16 + l4r) * 1024 + (c + 1) * 64 + s_s2 * 32 + l4c,
                 (void*)(W2n + (s_s2 * 128 + s_rg * 16) * 32));
        }
        // ---- ffn1 (swapped): D[hid 16][tok 32], K=256 from regs ----
        f32x4 acc1[2] = {};
#pragma unroll
        for (int ks = 0; ks < 8; ++ks) {
            bf16x8 w1f = *(const bf16x8*)(W1c + (ks * 64 + wn * 16 + lm) * 32 + q * 8);
#pragma unroll
            for (int mt = 0; mt < 2; ++mt)
                acc1[mt] = __builtin_amdgcn_mfma_f32_16x16x32_bf16(
                    w1f, areg[mt][ks], acc1[mt], 0, 0, 0);
        }
        // ---- gelu + pack -> Gs: lane holds tok=lm, hid n0..n0+3 ----
#pragma unroll
        for (int mt = 0; mt < 2; ++mt) {
            float g0 = gelu_e(acc1[mt][0]), g1 = gelu_e(acc1[mt][1]);
            float g2 = gelu_e(acc1[mt][2]), g3 = gelu_e(acc1[mt][3]);
            unsigned p0, p1;
            asm("v_cvt_pk_bf16_f32 %0, %1, %2" : "=v"(p0) : "v"(g0), "v"(g1));
            asm("v_cvt_pk_bf16_f32 %0, %1, %2" : "=v"(p1) : "v"(g2), "v"(g3));
            int tok = wm * 32 + mt * 16 + lm;
            int slot = (wn * 2 + (q >> 1)) ^ (tok & 7);   // n0=wn*16+q*4; slot16=n0>>3
            u32x2 pk; pk[0] = p0; pk[1] = p1;
            *(u32x2*)(Gs + tok * 64 + slot * 8 + (q & 1) * 4) = pk;
        }
        __syncthreads();   // Gs visible to all waves
        // ---- ffn2: D[tok 32][col 32] per wave, K=64 from Gs ----
#pragma unroll
        for (int ks = 0; ks < 2; ++ks) {
            bf16x8 pa[2], wf[2];
#pragma unroll
            for (int mt = 0; mt < 2; ++mt) {
                int tok = wm * 32 + mt * 16 + lm;
                pa[mt] = *(const bf16x8*)(Gs + tok * 64 + (((ks * 4 + q) ^ (tok & 7)) * 8));
            }
#pragma unroll
            for (int nt = 0; nt < 2; ++nt)
                wf[nt] = *(const bf16x8*)(W2c + (ks * 128 + wn * 32 + nt * 16 + lm) * 32 + q * 8);
#pragma unroll
            for (int mt = 0; mt < 2; ++mt)
#pragma unroll
                for (int nt = 0; nt < 2; ++nt)
                    acc2[mt][nt] = __builtin_amdgcn_mfma_f32_16x16x32_bf16(
                        pa[mt], wf[nt], acc2[mt][nt], 0, 0, 0);
        }
        __syncthreads();   // Gs reads done; drains vmcnt -> next weights landed
    }

    // ---- LN + residual epilogue (stats exchange overlaid on Gs) ----
    float* stats = (float*)Gs;                   // [128][8] = 4KB
#pragma unroll
    for (int mt = 0; mt < 2; ++mt)
#pragma unroll
        for (int r = 0; r < 4; ++r) {
            float s1 = 0.f, s2 = 0.f;
#pragma unroll
            for (int nt = 0; nt < 2; ++nt) {
                float v = acc2[mt][nt][r];
                s1 += v; s2 += v * v;
            }
            s1 += __shfl_xor(s1, 1); s2 += __shfl_xor(s2, 1);
            s1 += __shfl_xor(s1, 2); s2 += __shfl_xor(s2, 2);
            s1 += __shfl_xor(s1, 4); s2 += __shfl_xor(s2, 4);
            s1 += __shfl_xor(s1, 8); s2 += __shfl_xor(s2, 8);
            if (lm == 0) {
                int row = wm * 32 + mt * 16 + q * 4 + r;
                stats[row * 8 + wn * 2] = s1;
                stats[row * 8 + wn * 2 + 1] = s2;
            }
        }
    __syncthreads();

    float gv[2], bv[2];
#pragma unroll
    for (int nt = 0; nt < 2; ++nt) {
        int col = wn * 32 + nt * 16 + lm;
        gv[nt] = g[col]; bv[nt] = bb[col];
    }
#pragma unroll
    for (int mt = 0; mt < 2; ++mt)
#pragma unroll
        for (int r = 0; r < 4; ++r) {
            int row = wm * 32 + mt * 16 + q * 4 + r;
            f32x4 st0 = *(const f32x4*)(stats + row * 8);
            f32x4 st1 = *(const f32x4*)(stats + row * 8 + 4);
            float s1 = st0[0] + st0[2] + st1[0] + st1[2];
            float s2 = st0[1] + st0[3] + st1[1] + st1[3];
            float mean = s1 * (1.f / 128.f);
            float var = fmaxf(s2 * (1.f / 128.f) - mean * mean, 0.f);
            float rs = rsqrtf(var + 1e-5f);
#pragma unroll
            for (int nt = 0; nt < 2; ++nt) {
                int col = wn * 32 + nt * 16 + lm;
                size_t gi = (size_t)(m0 + row) * 128 + col;
                outv[gi] = (acc2[mt][nt][r] - mean) * rs * gv[nt] + bv[nt] + resid[gi];
            }
        }
}

// ---------------------------------------------------------------------------
// Prep (merged): weight transposes write-coalesced; fp32->bf16 act cast.
// ---------------------------------------------------------------------------
__global__ void prep_all(const float* __restrict__ Wq, const float* __restrict__ Wk,
                         const float* __restrict__ Wv, const float* __restrict__ Wm,
                         const float* __restrict__ W1, const float* __restrict__ W2,
                         const float* __restrict__ src, const float* __restrict__ tgt,
                         u16* __restrict__ ws, u16* __restrict__ srcb,
                         u16* __restrict__ tgtb)
{
    int bx = blockIdx.x;
    if (bx < 1792) {
        int idx = bx * 256 + threadIdx.x;
        if (idx < 65536) {                       // Wq,Wk,Wv,Wm: 128x128
            int m = idx >> 14, e = idx & 16383;
            const float* sp = (m == 0) ? Wq : (m == 1) ? Wk : (m == 2) ? Wv : Wm;
            int n = e >> 7, k = e & 127;
            ws[m * 16384 + n * 128 + k] = f2b(sp[k * 128 + n]);
        } else if (idx < 327680) {               // W1 (256,1024) -> (1024,256)
            int e = idx - 65536;
            int n = e >> 8, k = e & 255;
            ws[65536 + n * 256 + k] = f2b(W1[k * 1024 + n]);
        } else {                                  // W2 (1024,128) -> (128,1024)
            int e = idx - 327680;
            int n = e >> 10, k = e & 1023;
            ws[327680 + n * 1024 + k] = f2b(W2[k * 128 + n]);
        }
    } else {
        int idx = (bx - 1792) * 256 + threadIdx.x;   // 0..2097151
        const float* s; u16* d; int i;
        if (idx < 1048576) { s = src; d = srcb; i = idx * 4; }
        else               { s = tgt; d = tgtb; i = (idx - 1048576) * 4; }
        f32x4 v = *(const f32x4*)(s + i);
        u16x4 o; o[0] = f2b(v[0]); o[1] = f2b(v[1]); o[2] = f2b(v[2]); o[3] = f2b(v[3]);
        *(u16x4*)(d + i) = o;
    }
}

// ---------------------------------------------------------------------------
// Workspace layout (u16 element offsets)
// ---------------------------------------------------------------------------
#define OFF_WQT  0u            // concat [WqT;WkT;WvT] 3x(128x128)
#define OFF_WMT  49152u
#define OFF_W1T  65536u
#define OFF_W2T  327680u
#define OFF_SRCB 458752u
#define OFF_TGTB 4653056u
#define OFF_QW   8847360u
#define OFF_KW   13041664u
#define OFF_VWT  17235968u
#define OFF_MSGB 21430272u     // bf16 msg, source-order; ends 25624576

extern "C" void kernel_launch(void* const* d_in, const int* in_sizes, int n_in,
                              void* d_out, int out_size, void* d_ws, size_t ws_size,
                              hipStream_t stream)
{
    (void)in_sizes; (void)n_in; (void)out_size; (void)ws_size;
    const float* source = (const float*)d_in[0];
    const float* target = (const float*)d_in[1];
    const float* Wq = (const float*)d_in[2];
    const float* Wk = (const float*)d_in[3];
    const float* Wv = (const float*)d_in[4];
    const float* Wm = (const float*)d_in[5];
    const float* g1 = (const float*)d_in[6];
    const float* b1 = (const float*)d_in[7];
    const float* W1 = (const float*)d_in[8];
    const float* W2 = (const float*)d_in[9];
    const float* g2 = (const float*)d_in[10];
    const float* b2 = (const float*)d_in[11];
    u16* ws = (u16*)d_ws;
    float* out = (float*)d_out;

    prep_all<<<9984, 256, 0, stream>>>(Wq, Wk, Wv, Wm, W1, W2, source, target,
                                       ws, ws + OFF_SRCB, ws + OFF_TGTB);
    gemm_qkv<<<dim3(256, 3), 256, 0, stream>>>(
        ws + OFF_SRCB, ws + OFF_TGTB, ws + OFF_WQT,
        ws + OFF_QW, ws + OFF_KW, ws + OFF_VWT);
    attn_msg<<<512, 256, 0, stream>>>(
        ws + OFF_QW, ws + OFF_KW, ws + OFF_VWT, ws + OFF_WMT, g1, b1,
        ws + OFF_MSGB);
    fused_ffn<<<256, 1024, 0, stream>>>(
        ws + OFF_SRCB, ws + OFF_MSGB, ws + OFF_W1T, ws + OFF_W2T,
        g2, b2, source, out);
}

// Round 3
// 191.458 us; speedup vs baseline: 1.0867x; 1.0038x over previous
//
#include <hip/hip_runtime.h>
#include <math.h>
#include <stdint.h>

// ---------------------------------------------------------------------------
// TransformerLayer (Swin-style) on MI355X. FP32 I/O; bf16 MFMA internals.
// B=2, H=W=128, C=128, NS=8 -> 64 windows x 256 tokens; HID=1024.
// R10: fused_ffn software-pipelined: ONE barrier/chunk. Iter c runs
//      ffn1(c+1)->Gs[nb] and ffn2(c)<-Gs[cb] in one phase (MFMA/VALU
//      overlap); W1 staged 2 ahead, W2 1 ahead (buffer-lifetime-safe);
//      pointer-bump staging addresses; unroll 2 for static buffer selects.
// ---------------------------------------------------------------------------

typedef unsigned short u16;
typedef __attribute__((ext_vector_type(8))) short bf16x8;   // 8 bf16 (4 VGPRs)
typedef __attribute__((ext_vector_type(4))) float f32x4;
typedef __attribute__((ext_vector_type(4))) short u16x4;
typedef __attribute__((ext_vector_type(2))) unsigned int u32x2;

__device__ __forceinline__ u16 f2b(float f) {
    unsigned int i = __float_as_uint(f);
    unsigned int r = (i + 0x7fffu + ((i >> 16) & 1u)) >> 16;
    return (u16)r;
}

// gelu via A-S 7.1.28 erf (|eps|<=5e-4): ONE transcendental (rcp).
__device__ __forceinline__ float gelu_e(float x) {
    float y = fabsf(x) * 0.70710678118f;
    float u = fmaf(y, fmaf(y, fmaf(y, fmaf(y, 0.078108f, 0.000972f),
                                   0.230389f), 0.278393f), 1.0f);
    u = u * u; u = u * u;
    float r = __builtin_amdgcn_rcpf(u);
    return fmaxf(x, 0.f) - 0.5f * fabsf(x) * r;
}

// 16B async global->LDS (m97-verified). LDS dest wave-uniform base + lane*16.
__device__ __forceinline__ void cp16(const void* g, void* l) {
    auto* gp = reinterpret_cast<const __attribute__((address_space(1))) unsigned int*>(
        reinterpret_cast<uintptr_t>(g));
    auto* lp = reinterpret_cast<__attribute__((address_space(3))) unsigned int*>(
        reinterpret_cast<uintptr_t>(l));
    __builtin_amdgcn_global_load_lds(gp, lp, 16, 0, 0);
}

// window row (b*16384 + win*256 + t) -> source-order row (b*16384 + h*128 + w)
__device__ __forceinline__ int win_map(int gm) {
    int b = gm >> 14, rr = gm & 16383;
    int win = rr >> 8, t = rr & 255;
    int wi = win >> 3, wj = win & 7, i = t >> 4, j = t & 15;
    int h = (wi * 16 + i + 8) & 127;
    int w = (wj * 16 + j + 8) & 127;
    return (b << 14) + h * 128 + w;
}

// ---------------------------------------------------------------------------
// Fused QKV: grid (256, 3). y=0: q=src@Wq, y=1: k=tgt@Wk (window layouts),
// y=2: v=tgt@Wv stored transposed per window. K=128 fully LDS-resident.
// ---------------------------------------------------------------------------
__global__ __launch_bounds__(256, 2)
void gemm_qkv(const u16* __restrict__ srcb, const u16* __restrict__ tgtb,
              const u16* __restrict__ Bt, u16* __restrict__ qw,
              u16* __restrict__ kw, u16* __restrict__ vwt)
{
    __shared__ __align__(16) u16 SMEM[32768];   // As[4][128][32] | Bs[4][128][32]
    u16* As = SMEM;
    u16* Bs = SMEM + 16384;
    u16* Ts = SMEM;                              // 128x136 epilogue overlay

    const int tid = threadIdx.x;
    const int w = tid >> 6, lane = tid & 63;
    const int lm = lane & 15, q = lane >> 4;
    const int wm = w >> 1, wn = w & 1;
    const int m0 = blockIdx.x * 128;
    const int y = blockIdx.y;
    const u16* Ab = (y == 0) ? srcb : tgtb;

#pragma unroll
    for (int s = 0; s < 4; ++s)
#pragma unroll
        for (int i = 0; i < 2; ++i) {
            int row = w * 32 + i * 16 + (lane >> 2);
            int kc = s * 32 + (lane & 3) * 8;
            cp16(Ab + (size_t)win_map(m0 + row) * 128 + kc,
                 (void*)(As + (s * 128 + w * 32 + i * 16) * 32));
            cp16(Bt + (size_t)(y * 128 + row) * 128 + kc,
                 (void*)(Bs + (s * 128 + w * 32 + i * 16) * 32));
        }
    __syncthreads();

    f32x4 acc[4][4] = {};
#pragma unroll
    for (int s = 0; s < 4; ++s) {
        bf16x8 af[4], bfr[4];
#pragma unroll
        for (int t = 0; t < 4; ++t)
            af[t] = *(const bf16x8*)(As + (s * 128 + wm * 64 + t * 16 + lm) * 32 + q * 8);
#pragma unroll
        for (int t = 0; t < 4; ++t)
            bfr[t] = *(const bf16x8*)(Bs + (s * 128 + wn * 64 + t * 16 + lm) * 32 + q * 8);
#pragma unroll
        for (int mt = 0; mt < 4; ++mt)
#pragma unroll
            for (int nt = 0; nt < 4; ++nt)
                acc[mt][nt] = __builtin_amdgcn_mfma_f32_16x16x32_bf16(
                    af[mt], bfr[nt], acc[mt][nt], 0, 0, 0);
    }

    __syncthreads();
#pragma unroll
    for (int mt = 0; mt < 4; ++mt)
#pragma unroll
        for (int nt = 0; nt < 4; ++nt)
#pragma unroll
            for (int r = 0; r < 4; ++r) {
                int rowl = wm * 64 + mt * 16 + q * 4 + r;
                int col = wn * 64 + nt * 16 + lm;
                int idx = (y == 2) ? col * 136 + rowl : rowl * 136 + col;
                Ts[idx] = f2b(acc[mt][nt][r]);
            }
    __syncthreads();
    const int c8 = (tid & 15) * 8;
#pragma unroll
    for (int i = 0; i < 8; ++i) {
        int rr = i * 16 + (tid >> 4);
        bf16x8 t = *(const bf16x8*)(Ts + rr * 136 + c8);
        if (y == 2) {
            int wix = m0 >> 8, tok0 = m0 & 255;   // vwT[(b*64+win)*128+ch][tok]
            *(bf16x8*)(vwt + (size_t)wix * 32768 + (size_t)rr * 256 + tok0 + c8) = t;
        } else {
            u16* Cv = (y == 0) ? qw : kw;
            *(bf16x8*)(Cv + (size_t)(m0 + rr) * 128 + c8) = t;
        }
    }
}

// ---------------------------------------------------------------------------
// Fused attention + msg-proj + LayerNorm, fully LDS-staged operands.
// One block = 64 Q rows of a window; grid 512. LDS: Ps 33.8KB + B32 32KB.
// ---------------------------------------------------------------------------
__global__ __launch_bounds__(256, 2)
void attn_msg(const u16* __restrict__ qw, const u16* __restrict__ kw,
              const u16* __restrict__ vt, const u16* __restrict__ wmt,
              const float* __restrict__ g, const float* __restrict__ bb,
              u16* __restrict__ msgb)
{
    __shared__ __align__(16) u16 Ps[64 * 264];   // P (stride 264); Q/Ot overlays
    __shared__ __align__(16) u16 B32[16384];     // 32KB staging buffer

    const int tid = threadIdx.x, w = tid >> 6, lane = tid & 63;
    const int lm = lane & 15, q = lane >> 4;
    const int l4r = lane >> 2, l4c = (lane & 3) * 8;
    const int bid = blockIdx.x;
    const int qc = bid & 3, win = (bid >> 2) & 63, b = bid >> 8;
    const int wi = win >> 3, wj = win & 7;
    const int q0 = qc * 64;
    const size_t wbase = (size_t)(b * 64 + win);
    const u16* kwb = kw + wbase * 256 * 128;
    const u16* qwb = qw + wbase * 256 * 128;
    const u16* vtb = vt + wbase * 128 * 256;

    // ---- stage Q (Ps overlay, [4 kt][64 row][32]) + K tok[0,128) ----
    u16* Qs = Ps;
#pragma unroll
    for (int i = 0; i < 4; ++i)
        cp16(qwb + (size_t)(q0 + w * 16 + l4r) * 128 + i * 32 + l4c,
             (void*)(Qs + (i * 64 + w * 16) * 32));
#pragma unroll
    for (int s = 0; s < 4; ++s)
#pragma unroll
        for (int i = 0; i < 2; ++i) {
            int tok = w * 32 + i * 16 + l4r;
            cp16(kwb + (size_t)tok * 128 + s * 32 + l4c,
                 (void*)(B32 + (s * 128 + w * 32 + i * 16) * 32));
        }
    __syncthreads();

    bf16x8 af[4];
#pragma unroll
    for (int kt = 0; kt < 4; ++kt)
        af[kt] = *(const bf16x8*)(Qs + (kt * 64 + w * 16 + lm) * 32 + q * 8);

    f32x4 s[16];
#pragma unroll
    for (int nt = 0; nt < 16; ++nt) { f32x4 z = {0.f, 0.f, 0.f, 0.f}; s[nt] = z; }
#pragma unroll
    for (int kt = 0; kt < 4; ++kt)
#pragma unroll
        for (int nt = 0; nt < 8; ++nt) {
            bf16x8 bf = *(const bf16x8*)(B32 + (kt * 128 + nt * 16 + lm) * 32 + q * 8);
            s[nt] = __builtin_amdgcn_mfma_f32_16x16x32_bf16(af[kt], bf, s[nt], 0, 0, 0);
        }
    __syncthreads();
    // ---- K tok[128,256) ----
#pragma unroll
    for (int ss = 0; ss < 4; ++ss)
#pragma unroll
        for (int i = 0; i < 2; ++i) {
            int tok = 128 + w * 32 + i * 16 + l4r;
            cp16(kwb + (size_t)tok * 128 + ss * 32 + l4c,
                 (void*)(B32 + (ss * 128 + w * 32 + i * 16) * 32));
        }
    __syncthreads();
#pragma unroll
    for (int kt = 0; kt < 4; ++kt)
#pragma unroll
        for (int nt = 8; nt < 16; ++nt) {
            bf16x8 bf = *(const bf16x8*)(B32 + (kt * 128 + (nt - 8) * 16 + lm) * 32 + q * 8);
            s[nt] = __builtin_amdgcn_mfma_f32_16x16x32_bf16(af[kt], bf, s[nt], 0, 0, 0);
        }
    __syncthreads();   // B32 reads done -> free for V

    // ---- issue V tok[0,128) load, then softmax (overlap) ----
#pragma unroll
    for (int tt = 0; tt < 4; ++tt)
#pragma unroll
        for (int i = 0; i < 2; ++i) {
            int ch = w * 32 + i * 16 + l4r;
            cp16(vtb + (size_t)ch * 256 + tt * 32 + l4c,
                 (void*)(B32 + (tt * 128 + w * 32 + i * 16) * 32));
        }

    // analytic Swin mask + softmax (regs), P -> Ps
    int idk[16];
#pragma unroll
    for (int nt = 0; nt < 16; ++nt) {
        int rh = (wi == 7) ? ((nt >= 8) ? 2 : 1) : 0;
        int rw = (wj == 7) ? ((lm >= 8) ? 2 : 1) : 0;
        idk[nt] = rh * 3 + rw;
    }
    const float scale = 0.08838834764831845f;
#pragma unroll
    for (int r = 0; r < 4; ++r) {
        int tq = q0 + w * 16 + q * 4 + r;
        int iq = tq >> 4, jq = tq & 15;
        int rhq = (wi == 7) ? ((iq >= 8) ? 2 : 1) : 0;
        int rwq = (wj == 7) ? ((jq >= 8) ? 2 : 1) : 0;
        int idq = rhq * 3 + rwq;
        float sv[16];
        float mx = -1e30f;
#pragma unroll
        for (int nt = 0; nt < 16; ++nt) {
            float x = s[nt][r] * scale + ((idq != idk[nt]) ? -100.f : 0.f);
            sv[nt] = x; mx = fmaxf(mx, x);
        }
        mx = fmaxf(mx, __shfl_xor(mx, 1));
        mx = fmaxf(mx, __shfl_xor(mx, 2));
        mx = fmaxf(mx, __shfl_xor(mx, 4));
        mx = fmaxf(mx, __shfl_xor(mx, 8));
        float sum = 0.f;
#pragma unroll
        for (int nt = 0; nt < 16; ++nt) { float e = __expf(sv[nt] - mx); sv[nt] = e; sum += e; }
        sum += __shfl_xor(sum, 1);
        sum += __shfl_xor(sum, 2);
        sum += __shfl_xor(sum, 4);
        sum += __shfl_xor(sum, 8);
        float inv = 1.0f / sum;
#pragma unroll
        for (int nt = 0; nt < 16; ++nt)
            Ps[(w * 16 + q * 4 + r) * 264 + nt * 16 + lm] = f2b(sv[nt] * inv);
    }
    __syncthreads();   // V0 loaded (barrier drains vmcnt) + P visible

    // ---- PV tok[0,128) ----
    f32x4 o[8];
#pragma unroll
    for (int nt = 0; nt < 8; ++nt) { f32x4 z = {0.f, 0.f, 0.f, 0.f}; o[nt] = z; }
#pragma unroll
    for (int tt = 0; tt < 4; ++tt) {
        bf16x8 pf = *(const bf16x8*)(Ps + (w * 16 + lm) * 264 + tt * 32 + q * 8);
#pragma unroll
        for (int nt = 0; nt < 8; ++nt) {
            bf16x8 vf = *(const bf16x8*)(B32 + (tt * 128 + nt * 16 + lm) * 32 + q * 8);
            o[nt] = __builtin_amdgcn_mfma_f32_16x16x32_bf16(pf, vf, o[nt], 0, 0, 0);
        }
    }
    __syncthreads();
    // ---- V tok[128,256) ----
#pragma unroll
    for (int tt = 0; tt < 4; ++tt)
#pragma unroll
        for (int i = 0; i < 2; ++i) {
            int ch = w * 32 + i * 16 + l4r;
            cp16(vtb + (size_t)ch * 256 + 128 + tt * 32 + l4c,
                 (void*)(B32 + (tt * 128 + w * 32 + i * 16) * 32));
        }
    __syncthreads();
#pragma unroll
    for (int tt = 4; tt < 8; ++tt) {
        bf16x8 pf = *(const bf16x8*)(Ps + (w * 16 + lm) * 264 + tt * 32 + q * 8);
#pragma unroll
        for (int nt = 0; nt < 8; ++nt) {
            bf16x8 vf = *(const bf16x8*)(B32 + ((tt - 4) * 128 + nt * 16 + lm) * 32 + q * 8);
            o[nt] = __builtin_amdgcn_mfma_f32_16x16x32_bf16(pf, vf, o[nt], 0, 0, 0);
        }
    }
    __syncthreads();   // V reads + P reads done

    // ---- issue Wm stage; write O -> Ot (Ps overlay, A-layout) ----
#pragma unroll
    for (int ss = 0; ss < 4; ++ss)
#pragma unroll
        for (int i = 0; i < 2; ++i) {
            int n = w * 32 + i * 16 + l4r;
            cp16(wmt + (size_t)n * 128 + ss * 32 + l4c,
                 (void*)(B32 + (ss * 128 + w * 32 + i * 16) * 32));
        }
    u16* Ot = Ps;   // [64][136]
#pragma unroll
    for (int r = 0; r < 4; ++r) {
        int rl = w * 16 + q * 4 + r;
#pragma unroll
        for (int nt = 0; nt < 8; ++nt)
            Ot[rl * 136 + nt * 16 + lm] = f2b(o[nt][r]);
    }
    __syncthreads();

    // ---- msg = O @ WmT^T (all-LDS) ----
    f32x4 macc[8];
#pragma unroll
    for (int n2 = 0; n2 < 8; ++n2) { f32x4 z = {0.f, 0.f, 0.f, 0.f}; macc[n2] = z; }
#pragma unroll
    for (int kt = 0; kt < 4; ++kt) {
        bf16x8 paf = *(const bf16x8*)(Ot + (w * 16 + lm) * 136 + kt * 32 + q * 8);
#pragma unroll
        for (int n2 = 0; n2 < 8; ++n2) {
            bf16x8 wf = *(const bf16x8*)(B32 + (kt * 128 + n2 * 16 + lm) * 32 + q * 8);
            macc[n2] = __builtin_amdgcn_mfma_f32_16x16x32_bf16(paf, wf, macc[n2], 0, 0, 0);
        }
    }

    // ---- row LN + store (source-order rows) ----
    float gv[8], bv[8];
#pragma unroll
    for (int n2 = 0; n2 < 8; ++n2) {
        int col = n2 * 16 + lm;
        gv[n2] = g[col]; bv[n2] = bb[col];
    }
#pragma unroll
    for (int r = 0; r < 4; ++r) {
        float s1 = 0.f, s2 = 0.f;
#pragma unroll
        for (int n2 = 0; n2 < 8; ++n2) {
            float v = macc[n2][r];
            s1 += v; s2 += v * v;
        }
        s1 += __shfl_xor(s1, 1); s2 += __shfl_xor(s2, 1);
        s1 += __shfl_xor(s1, 2); s2 += __shfl_xor(s2, 2);
        s1 += __shfl_xor(s1, 4); s2 += __shfl_xor(s2, 4);
        s1 += __shfl_xor(s1, 8); s2 += __shfl_xor(s2, 8);
        float mean = s1 * (1.f / 128.f);
        float var = fmaxf(s2 * (1.f / 128.f) - mean * mean, 0.f);
        float rs = rsqrtf(var + 1e-5f);
        int t = q0 + w * 16 + q * 4 + r;
        int ii = t >> 4, jj = t & 15;
        int h = (wi * 16 + ii + 8) & 127;
        int w2 = (wj * 16 + jj + 8) & 127;
        size_t orow = ((size_t)b * 16384 + h * 128 + w2) * 128;
#pragma unroll
        for (int n2 = 0; n2 < 8; ++n2)
            msgb[orow + n2 * 16 + lm] = f2b((macc[n2][r] - mean) * rs * gv[n2] + bv[n2]);
    }
}

// ---------------------------------------------------------------------------
// FUSED FFN R10: out = resid + LN(gelu(cat(src,msg)@W1)@W2).
// 1024 thr (16 waves, 4/SIMD), 128KB LDS, grid 256 (128 rows/block).
// Software-pipelined: iter c = { stage W1(c+2)/W2(c+1); ffn1(c+1)->Gs[nb];
// ffn2(c)<-Gs[cb]; barrier }. ONE barrier per chunk; ffn2 MFMAs interleave
// with ffn1 chain + gelu VALU. Pointer-bump staging; unroll 2 for static
// buffer selects. A in registers (AGPR side of unified file).
// ---------------------------------------------------------------------------
__global__ __launch_bounds__(1024, 4)
void fused_ffn(const u16* __restrict__ A0, const u16* __restrict__ A1,
               const u16* __restrict__ W1T, const u16* __restrict__ W2T,
               const float* __restrict__ g, const float* __restrict__ bb,
               const float* __restrict__ resid, float* __restrict__ outv)
{
    __shared__ __align__(16) u16 W1s[32768];    // [2 buf][8 ks][64 hid][32] 64KB
    __shared__ __align__(16) u16 W2s[16384];    // [2 buf][2 ks][128 col][32] 32KB
    __shared__ __align__(16) u16 Gs[16384];     // [2 buf][128 tok][64 k] swz 32KB

    const int tid = threadIdx.x;
    const int w = tid >> 6, lane = tid & 63;
    const int lm = lane & 15, q = lane >> 4;
    const int l4r = lane >> 2, l4c = (lane & 3) * 8;
    const int wm = w >> 2, wn = w & 3;          // token-block 32 / hid16|col32
    const int m0 = blockIdx.x * 128;

    const int s_ks = w >> 1, s_hh = (w & 1) * 32;   // W1 stage mapping
    const int s_s2 = w >> 3, s_rg = w & 7;          // W2 stage mapping

    // staging source pointers (bumped by constant stride per chunk)
    const u16* w1p = W1T + (size_t)(s_hh + l4r) * 256 + s_ks * 32 + l4c;
    const u16* w2p = W2T + (size_t)(s_rg * 16 + l4r) * 1024 + s_s2 * 32 + l4c;
    u16* const w1d0 = W1s + (s_ks * 64 + s_hh) * 32;
    u16* const w1d1 = w1d0 + 16384;
    u16* const w2d0 = W2s + (s_s2 * 128 + s_rg * 16) * 32;
    u16* const w2d1 = w2d0 + 8192;

    // ---- A -> regs (one-time) ----
    bf16x8 areg[2][8];
#pragma unroll
    for (int mt = 0; mt < 2; ++mt)
#pragma unroll
        for (int ks = 0; ks < 8; ++ks) {
            const u16* Ab = (ks < 4) ? A0 : A1;
            areg[mt][ks] = *(const bf16x8*)(
                Ab + (size_t)(m0 + wm * 32 + mt * 16 + lm) * 128 + (ks & 3) * 32 + q * 8);
        }

    // ---- prologue: S(0) -> buf0; barrier; S_W1(1) -> buf1; ffn1(0)->Gs0 ----
    cp16(w1p, w1d0); cp16(w1p + 16 * 256, w1d0 + 512);
    cp16(w2p, w2d0);
    w1p += 16384; w2p += 64;
    __syncthreads();                              // W(0) landed

    cp16(w1p, w1d1); cp16(w1p + 16 * 256, w1d1 + 512);
    w1p += 16384;
    {
        f32x4 acc1[2] = {};
#pragma unroll
        for (int ks = 0; ks < 8; ++ks) {
            bf16x8 w1f = *(const bf16x8*)(W1s + (ks * 64 + wn * 16 + lm) * 32 + q * 8);
#pragma unroll
            for (int mt = 0; mt < 2; ++mt)
                acc1[mt] = __builtin_amdgcn_mfma_f32_16x16x32_bf16(
                    w1f, areg[mt][ks], acc1[mt], 0, 0, 0);
        }
#pragma unroll
        for (int mt = 0; mt < 2; ++mt) {
            float g0 = gelu_e(acc1[mt][0]), g1 = gelu_e(acc1[mt][1]);
            float g2 = gelu_e(acc1[mt][2]), g3 = gelu_e(acc1[mt][3]);
            unsigned p0, p1;
            asm("v_cvt_pk_bf16_f32 %0, %1, %2" : "=v"(p0) : "v"(g0), "v"(g1));
            asm("v_cvt_pk_bf16_f32 %0, %1, %2" : "=v"(p1) : "v"(g2), "v"(g3));
            int tok = wm * 32 + mt * 16 + lm;
            int slot = (wn * 2 + (q >> 1)) ^ (tok & 7);
            u32x2 pk; pk[0] = p0; pk[1] = p1;
            *(u32x2*)(Gs + tok * 64 + slot * 8 + (q & 1) * 4) = pk;
        }
    }
    __syncthreads();                              // Gs0 visible; W1(1) landed

    // ---- main pipeline: one barrier per iter ----
    f32x4 acc2[2][2] = {};                        // 32x32 out tile per wave
#pragma unroll 2
    for (int c = 0; c < 16; ++c) {
        const int cb = c & 1, nb = cb ^ 1;
        // stage W1(c+2) -> buf[cb] (freed: ffn1(c) drained last barrier)
        if (c + 2 < 16) {
            u16* d = cb ? w1d1 : w1d0;
            cp16(w1p, d); cp16(w1p + 16 * 256, d + 512);
        }
        // stage W2(c+1) -> buf[nb] (freed: ffn2(c-1) drained last barrier)
        if (c + 1 < 16) {
            u16* d = nb ? w2d1 : w2d0;
            cp16(w2p, d);
        }
        w1p += 16384; w2p += 64;

        // ---- ffn1(c+1): W1s buf[nb] (ready) -> gelu -> Gs[nb] ----
        if (c + 1 < 16) {
            const u16* W1c = W1s + nb * 16384;
            f32x4 acc1[2] = {};
#pragma unroll
            for (int ks = 0; ks < 8; ++ks) {
                bf16x8 w1f = *(const bf16x8*)(W1c + (ks * 64 + wn * 16 + lm) * 32 + q * 8);
#pragma unroll
                for (int mt = 0; mt < 2; ++mt)
                    acc1[mt] = __builtin_amdgcn_mfma_f32_16x16x32_bf16(
                        w1f, areg[mt][ks], acc1[mt], 0, 0, 0);
            }
            u16* Gw = Gs + nb * 8192;
#pragma unroll
            for (int mt = 0; mt < 2; ++mt) {
                float g0 = gelu_e(acc1[mt][0]), g1 = gelu_e(acc1[mt][1]);
                float g2 = gelu_e(acc1[mt][2]), g3 = gelu_e(acc1[mt][3]);
                unsigned p0, p1;
                asm("v_cvt_pk_bf16_f32 %0, %1, %2" : "=v"(p0) : "v"(g0), "v"(g1));
                asm("v_cvt_pk_bf16_f32 %0, %1, %2" : "=v"(p1) : "v"(g2), "v"(g3));
                int tok = wm * 32 + mt * 16 + lm;
                int slot = (wn * 2 + (q >> 1)) ^ (tok & 7);
                u32x2 pk; pk[0] = p0; pk[1] = p1;
                *(u32x2*)(Gw + tok * 64 + slot * 8 + (q & 1) * 4) = pk;
            }
        }

        // ---- ffn2(c): Gs[cb] + W2s buf[cb] -> acc2 (independent chain) ----
        {
            const u16* W2c = W2s + cb * 8192;
            const u16* Gr = Gs + cb * 8192;
#pragma unroll
            for (int ks = 0; ks < 2; ++ks) {
                bf16x8 pa[2], wf[2];
#pragma unroll
                for (int mt = 0; mt < 2; ++mt) {
                    int tok = wm * 32 + mt * 16 + lm;
                    pa[mt] = *(const bf16x8*)(Gr + tok * 64 + (((ks * 4 + q) ^ (tok & 7)) * 8));
                }
#pragma unroll
                for (int nt = 0; nt < 2; ++nt)
                    wf[nt] = *(const bf16x8*)(W2c + (ks * 128 + wn * 32 + nt * 16 + lm) * 32 + q * 8);
#pragma unroll
                for (int mt = 0; mt < 2; ++mt)
#pragma unroll
                    for (int nt = 0; nt < 2; ++nt)
                        acc2[mt][nt] = __builtin_amdgcn_mfma_f32_16x16x32_bf16(
                            pa[mt], wf[nt], acc2[mt][nt], 0, 0, 0);
            }
        }
        __syncthreads();   // drains vmcnt (staged W landed); Gs[nb] visible;
                           // frees W1[cb]/W2[nb]/Gs[cb] for next iter
    }

    // ---- LN + residual epilogue (stats exchange overlaid on Gs) ----
    float* stats = (float*)Gs;                   // [128][8] = 4KB
#pragma unroll
    for (int mt = 0; mt < 2; ++mt)
#pragma unroll
        for (int r = 0; r < 4; ++r) {
            float s1 = 0.f, s2 = 0.f;
#pragma unroll
            for (int nt = 0; nt < 2; ++nt) {
                float v = acc2[mt][nt][r];
                s1 += v; s2 += v * v;
            }
            s1 += __shfl_xor(s1, 1); s2 += __shfl_xor(s2, 1);
            s1 += __shfl_xor(s1, 2); s2 += __shfl_xor(s2, 2);
            s1 += __shfl_xor(s1, 4); s2 += __shfl_xor(s2, 4);
            s1 += __shfl_xor(s1, 8); s2 += __shfl_xor(s2, 8);
            if (lm == 0) {
                int row = wm * 32 + mt * 16 + q * 4 + r;
                stats[row * 8 + wn * 2] = s1;
                stats[row * 8 + wn * 2 + 1] = s2;
            }
        }
    __syncthreads();

    float gv[2], bv[2];
#pragma unroll
    for (int nt = 0; nt < 2; ++nt) {
        int col = wn * 32 + nt * 16 + lm;
        gv[nt] = g[col]; bv[nt] = bb[col];
    }
#pragma unroll
    for (int mt = 0; mt < 2; ++mt)
#pragma unroll
        for (int r = 0; r < 4; ++r) {
            int row = wm * 32 + mt * 16 + q * 4 + r;
            f32x4 st0 = *(const f32x4*)(stats + row * 8);
            f32x4 st1 = *(const f32x4*)(stats + row * 8 + 4);
            float s1 = st0[0] + st0[2] + st1[0] + st1[2];
            float s2 = st0[1] + st0[3] + st1[1] + st1[3];
            float mean = s1 * (1.f / 128.f);
            float var = fmaxf(s2 * (1.f / 128.f) - mean * mean, 0.f);
            float rs = rsqrtf(var + 1e-5f);
#pragma unroll
            for (int nt = 0; nt < 2; ++nt) {
                int col = wn * 32 + nt * 16 + lm;
                size_t gi = (size_t)(m0 + row) * 128 + col;
                outv[gi] = (acc2[mt][nt][r] - mean) * rs * gv[nt] + bv[nt] + resid[gi];
            }
        }
}

// ---------------------------------------------------------------------------
// Prep (merged): weight transposes write-coalesced; fp32->bf16 act cast.
// ---------------------------------------------------------------------------
__global__ void prep_all(const float* __restrict__ Wq, const float* __restrict__ Wk,
                         const float* __restrict__ Wv, const float* __restrict__ Wm,
                         const float* __restrict__ W1, const float* __restrict__ W2,
                         const float* __restrict__ src, const float* __restrict__ tgt,
                         u16* __restrict__ ws, u16* __restrict__ srcb,
                         u16* __restrict__ tgtb)
{
    int bx = blockIdx.x;
    if (bx < 1792) {
        int idx = bx * 256 + threadIdx.x;
        if (idx < 65536) {                       // Wq,Wk,Wv,Wm: 128x128
            int m = idx >> 14, e = idx & 16383;
            const float* sp = (m == 0) ? Wq : (m == 1) ? Wk : (m == 2) ? Wv : Wm;
            int n = e >> 7, k = e & 127;
            ws[m * 16384 + n * 128 + k] = f2b(sp[k * 128 + n]);
        } else if (idx < 327680) {               // W1 (256,1024) -> (1024,256)
            int e = idx - 65536;
            int n = e >> 8, k = e & 255;
            ws[65536 + n * 256 + k] = f2b(W1[k * 1024 + n]);
        } else {                                  // W2 (1024,128) -> (128,1024)
            int e = idx - 327680;
            int n = e >> 10, k = e & 1023;
            ws[327680 + n * 1024 + k] = f2b(W2[k * 128 + n]);
        }
    } else {
        int idx = (bx - 1792) * 256 + threadIdx.x;   // 0..2097151
        const float* s; u16* d; int i;
        if (idx < 1048576) { s = src; d = srcb; i = idx * 4; }
        else               { s = tgt; d = tgtb; i = (idx - 1048576) * 4; }
        f32x4 v = *(const f32x4*)(s + i);
        u16x4 o; o[0] = f2b(v[0]); o[1] = f2b(v[1]); o[2] = f2b(v[2]); o[3] = f2b(v[3]);
        *(u16x4*)(d + i) = o;
    }
}

// ---------------------------------------------------------------------------
// Workspace layout (u16 element offsets)
// ---------------------------------------------------------------------------
#define OFF_WQT  0u            // concat [WqT;WkT;WvT] 3x(128x128)
#define OFF_WMT  49152u
#define OFF_W1T  65536u
#define OFF_W2T  327680u
#define OFF_SRCB 458752u
#define OFF_TGTB 4653056u
#define OFF_QW   8847360u
#define OFF_KW   13041664u
#define OFF_VWT  17235968u
#define OFF_MSGB 21430272u     // bf16 msg, source-order; ends 25624576

extern "C" void kernel_launch(void* const* d_in, const int* in_sizes, int n_in,
                              void* d_out, int out_size, void* d_ws, size_t ws_size,
                              hipStream_t stream)
{
    (void)in_sizes; (void)n_in; (void)out_size; (void)ws_size;
    const float* source = (const float*)d_in[0];
    const float* target = (const float*)d_in[1];
    const float* Wq = (const float*)d_in[2];
    const float* Wk = (const float*)d_in[3];
    const float* Wv = (const float*)d_in[4];
    const float* Wm = (const float*)d_in[5];
    const float* g1 = (const float*)d_in[6];
    const float* b1 = (const float*)d_in[7];
    const float* W1 = (const float*)d_in[8];
    const float* W2 = (const float*)d_in[9];
    const float* g2 = (const float*)d_in[10];
    const float* b2 = (const float*)d_in[11];
    u16* ws = (u16*)d_ws;
    float* out = (float*)d_out;

    prep_all<<<9984, 256, 0, stream>>>(Wq, Wk, Wv, Wm, W1, W2, source, target,
                                       ws, ws + OFF_SRCB, ws + OFF_TGTB);
    gemm_qkv<<<dim3(256, 3), 256, 0, stream>>>(
        ws + OFF_SRCB, ws + OFF_TGTB, ws + OFF_WQT,
        ws + OFF_QW, ws + OFF_KW, ws + OFF_VWT);
    attn_msg<<<512, 256, 0, stream>>>(
        ws + OFF_QW, ws + OFF_KW, ws + OFF_VWT, ws + OFF_WMT, g1, b1,
        ws + OFF_MSGB);
    fused_ffn<<<256, 1024, 0, stream>>>(
        ws + OFF_SRCB, ws + OFF_MSGB, ws + OFF_W1T, ws + OFF_W2T,
        g2, b2, source, out);
}